// Round 6
// baseline (220.593 us; speedup 1.0000x reference)
//
#include <hip/hip_runtime.h>
#include <math.h>

#define SCALING 0.125f

typedef __attribute__((ext_vector_type(8))) short short8;
typedef __attribute__((ext_vector_type(4))) float f32x4;

// round-to-nearest-even fp32 -> bf16
static __device__ __forceinline__ unsigned short bf16r(float x) {
  unsigned int u = __float_as_uint(x);
  u += 0x7fffu + ((u >> 16) & 1u);
  return (unsigned short)(u >> 16);
}
static __device__ __forceinline__ float bf16f(unsigned short h) {
  return __uint_as_float(((unsigned int)h) << 16);
}
// pack two fp32 -> bf16x2 via v_perm_b32 merge
static __device__ __forceinline__ unsigned int pk_bf16(float lo, float hi) {
  unsigned int ua = __float_as_uint(lo);
  unsigned int ub = __float_as_uint(hi);
  ua += 0x7fffu + ((ua >> 16) & 1u);
  ub += 0x7fffu + ((ub >> 16) & 1u);
  return __builtin_amdgcn_perm(ub, ua, 0x07060302u);
}

// ---------------------------------------------------------------------------
// Kernel 0: fp32 -> bf16 hi/lo split for [query; key; value; W; out_w].
// cvt layout (bf16 element index):
//   [0, 524288)        query   (1024 x 512)
//   [524288, 1048576)  key
//   [1048576, 1572864) value
//   [1572864, 2359296) in_proj_weight (1536 x 512)
//   [2359296, 2621440) out_w          (512 x 512)
// ---------------------------------------------------------------------------
__global__ __launch_bounds__(256)
void convert_kernel(const float* __restrict__ q, const float* __restrict__ k,
                    const float* __restrict__ v, const float* __restrict__ W,
                    const float* __restrict__ ow,
                    unsigned short* __restrict__ hi,
                    unsigned short* __restrict__ lo) {
  const int base = blockIdx.x * 1024 + threadIdx.x * 4;
  const float* src;
  int off = base;
  if (base < 524288)       { src = q; }
  else if (base < 1048576) { src = k;  off = base - 524288; }
  else if (base < 1572864) { src = v;  off = base - 1048576; }
  else if (base < 2359296) { src = W;  off = base - 1572864; }
  else                     { src = ow; off = base - 2359296; }
  float4 x = *(const float4*)&src[off];
  ushort4 h, l;
  h.x = bf16r(x.x); l.x = bf16r(x.x - bf16f(h.x));
  h.y = bf16r(x.y); l.y = bf16r(x.y - bf16f(h.y));
  h.z = bf16r(x.z); l.z = bf16r(x.z - bf16f(h.z));
  h.w = bf16r(x.w); l.w = bf16r(x.w - bf16f(h.w));
  *(ushort4*)&hi[base] = h;
  *(ushort4*)&lo[base] = l;
}

// ---------------------------------------------------------------------------
// Kernel A: in-projection GEMM via bf16 hi/lo MFMA (fp32-accurate:
// Ahi*Bhi + Ahi*Blo + Alo*Bhi). Fragments loaded straight from L2, no LDS.
// Fragment mapping identical to the verified score kernel:
//   A[m=n15][k=quad*8+j], B[n=n15][k=quad*8+j], D[m=quad*4+r][n=n15].
// Epilogue scatter (verified since R1):
//   j <  512 : q -> qh[i][t][hd] fp32 (scaled)   j<1024: k -> kh fp32
//   j < 1536 : v -> vh bf16
// ---------------------------------------------------------------------------
__global__ __launch_bounds__(256)
void projmm_kernel(const unsigned short* __restrict__ cvt_hi,
                   const unsigned short* __restrict__ cvt_lo,
                   const float* __restrict__ bias,
                   float* __restrict__ qh, float* __restrict__ kh,
                   unsigned short* __restrict__ vh) {
  const int n0 = blockIdx.x * 64;  // 0..1535
  const int g = n0 >> 9;           // 0=q,1=k,2=v
  const int w = threadIdx.x >> 6;
  const int lane = threadIdx.x & 63;
  const int quad = lane >> 4, n15 = lane & 15;
  const int m0 = blockIdx.y * 64 + w * 16;

  const unsigned short* __restrict__ Ah = cvt_hi + g * 524288;
  const unsigned short* __restrict__ Al = cvt_lo + g * 524288;
  const unsigned short* __restrict__ Bh = cvt_hi + 1572864;
  const unsigned short* __restrict__ Bl = cvt_lo + 1572864;

  f32x4 acc[4];
#pragma unroll
  for (int nt = 0; nt < 4; ++nt) acc[nt] = (f32x4){0.f, 0.f, 0.f, 0.f};

  const int arow = (m0 + n15) * 512;
  for (int k0 = 0; k0 < 512; k0 += 32) {
    const int kq = k0 + quad * 8;
    short8 ah = *(const short8*)&Ah[arow + kq];
    short8 al = *(const short8*)&Al[arow + kq];
#pragma unroll
    for (int nt = 0; nt < 4; ++nt) {
      const int brow = (n0 + nt * 16 + n15) * 512;
      short8 bh = *(const short8*)&Bh[brow + kq];
      short8 bl = *(const short8*)&Bl[brow + kq];
      acc[nt] = __builtin_amdgcn_mfma_f32_16x16x32_bf16(ah, bh, acc[nt], 0, 0, 0);
      acc[nt] = __builtin_amdgcn_mfma_f32_16x16x32_bf16(ah, bl, acc[nt], 0, 0, 0);
      acc[nt] = __builtin_amdgcn_mfma_f32_16x16x32_bf16(al, bh, acc[nt], 0, 0, 0);
    }
  }

#pragma unroll
  for (int nt = 0; nt < 4; ++nt) {
    const int j = n0 + nt * 16 + n15;
    const int jj = j & 511;
    const int head = jj >> 6;
    const int hd = jj & 63;
    const float bj = bias[j];
#pragma unroll
    for (int r = 0; r < 4; ++r) {
      const int row = m0 + quad * 4 + r;
      const int t = row >> 3;
      const int batch = row & 7;
      const int i = batch * 8 + head;
      const int idx = ((i << 7) + t) * 64 + hd;
      const float val = acc[nt][r] + bj;
      if (g == 0)      qh[idx] = val * SCALING;
      else if (g == 1) kh[idx] = val;
      else             vh[idx] = bf16r(val);
    }
  }
}

// ---------------------------------------------------------------------------
// Kernel B: one block per (batch, a, b-half), loops 8 heads. Bias fragment
// (head-invariant) preloaded ONCE into 32 VGPRs -> per-head epilogue is pure
// VALU. MFMA structure identical to verified R5 kernel.
// ---------------------------------------------------------------------------
__global__ __launch_bounds__(256)
void score_kernel(const float* __restrict__ qh,
                  const float* __restrict__ kh,
                  const unsigned short* __restrict__ vh,
                  const float* __restrict__ cbias,
                  float* __restrict__ fused) {
  __shared__ __align__(16) unsigned short Ks[64 * 72];
  __shared__ __align__(16) unsigned short Vs[128 * 72];

  const int bid = blockIdx.x;  // (batch*128 + a)*2 + bh
  const int bh = bid & 1;
  const int ab = bid >> 1;
  const int batch = ab >> 7;
  const int a = ab & 127;
  const int tid = threadIdx.x;
  const int w = tid >> 6;
  const int lane = tid & 63;
  const int quad = lane >> 4;
  const int n15 = lane & 15;
  const int col8 = (tid & 7) * 8;
  const int bglob = bh * 64 + w * 16 + n15;

  // preload bias fragment (head-invariant) into registers
  const float* __restrict__ bp = cbias + (size_t)ab * 16384;
  f32x4 biasReg[8];
#pragma unroll
  for (int ic = 0; ic < 8; ++ic)
    biasReg[ic] = *(const f32x4*)&bp[bglob * 128 + ic * 16 + quad * 4];

  for (int h = 0; h < 8; ++h) {
    const int i = batch * 8 + h;
    const float* __restrict__ kb = kh + (size_t)i * 8192 + (size_t)bh * 64 * 64;
    const uint4* __restrict__ vb4 = (const uint4*)(vh + (size_t)i * 8192);
    const float* __restrict__ qa = qh + ((size_t)i * 128 + a) * 64;

    f32x4 q0 = *(const f32x4*)&qa[col8];
    f32x4 q1 = *(const f32x4*)&qa[col8 + 4];
#pragma unroll
    for (int j = 0; j < 4; ++j) {
      const int gg = j * 256 + tid;
      const int row = gg >> 3;
      *(uint4*)&Vs[row * 72 + col8] = vb4[gg];
    }
#pragma unroll
    for (int j = 0; j < 2; ++j) {
      const int gg = j * 256 + tid;
      const int row = gg >> 3;
      f32x4 k0 = *(const f32x4*)&kb[8 * gg];
      f32x4 k1 = *(const f32x4*)&kb[8 * gg + 4];
      k0 *= q0;
      k1 *= q1;
      uint4 pk;
      pk.x = pk_bf16(k0[0], k0[1]);
      pk.y = pk_bf16(k0[2], k0[3]);
      pk.z = pk_bf16(k1[0], k1[1]);
      pk.w = pk_bf16(k1[2], k1[3]);
      *(uint4*)&Ks[row * 72 + col8] = pk;
    }
    __syncthreads();

    short8 bf0 = *(const short8*)&Ks[(w * 16 + n15) * 72 + quad * 8];
    short8 bf1 = *(const short8*)&Ks[(w * 16 + n15) * 72 + 32 + quad * 8];

    f32x4 acc[8];
#pragma unroll
    for (int ic = 0; ic < 8; ++ic) acc[ic] = (f32x4){0.f, 0.f, 0.f, 0.f};
#pragma unroll
    for (int ic = 0; ic < 8; ++ic) {
      short8 a0 = *(const short8*)&Vs[(ic * 16 + n15) * 72 + quad * 8];
      short8 a1 = *(const short8*)&Vs[(ic * 16 + n15) * 72 + 32 + quad * 8];
      acc[ic] = __builtin_amdgcn_mfma_f32_16x16x32_bf16(a0, bf0, acc[ic], 0, 0, 0);
      acc[ic] = __builtin_amdgcn_mfma_f32_16x16x32_bf16(a1, bf1, acc[ic], 0, 0, 0);
    }
    __syncthreads();

    float fsum = 0.f, fmx = -INFINITY;
#pragma unroll
    for (int ic = 0; ic < 8; ++ic) {
#pragma unroll
      for (int r = 0; r < 4; ++r) {
        const float v = acc[ic][r] + biasReg[ic][r];
        fsum += v;
        fmx = fmaxf(fmx, v);
      }
    }
    fsum += __shfl_xor(fsum, 16, 64);
    fmx = fmaxf(fmx, __shfl_xor(fmx, 16, 64));
    fsum += __shfl_xor(fsum, 32, 64);
    fmx = fmaxf(fmx, __shfl_xor(fmx, 32, 64));
    if (quad == 0)
      fused[((size_t)i * 128 + a) * 128 + bglob] = fsum * (1.0f / 128.0f) + fmx;
  }
}

// ---------------------------------------------------------------------------
// Kernel C: softmax over b + attn[i,a,:] = sum_b w[b]*q[i,b,:].
// Writes attn as bf16 hi/lo (row r = a*8+batch, col = head*64+hd) for the
// MFMA out-projection.
// ---------------------------------------------------------------------------
__global__ __launch_bounds__(64)
void softmax_attn_kernel(const float* __restrict__ fused,
                         const float* __restrict__ qh,
                         unsigned short* __restrict__ attn_hi,
                         unsigned short* __restrict__ attn_lo) {
  const int bid = blockIdx.x;  // i*128 + a
  const int i = bid >> 7;
  const int a = bid & 127;
  const int lane = threadIdx.x;
  const float* __restrict__ fr = fused + (size_t)bid * 128;
  float f0 = fr[lane], f1 = fr[lane + 64];
  float m = fmaxf(f0, f1);
#pragma unroll
  for (int off = 32; off >= 1; off >>= 1) m = fmaxf(m, __shfl_xor(m, off, 64));
  const float e0 = expf(f0 - m), e1 = expf(f1 - m);
  float s = e0 + e1;
#pragma unroll
  for (int off = 32; off >= 1; off >>= 1) s += __shfl_xor(s, off, 64);
  const float inv = 1.0f / s;
  __shared__ float w[128];
  w[lane] = e0 * inv;
  w[lane + 64] = e1 * inv;
  __syncthreads();
  const float* __restrict__ qp = qh + (size_t)i * 128 * 64 + lane;
  float acc = 0.0f;
#pragma unroll 4
  for (int b = 0; b < 128; b++) acc = fmaf(w[b], qp[b * 64], acc);
  const int batch = i >> 3, head = i & 7;
  const int idx = ((int)(a * 8 + batch)) * 512 + head * 64 + lane;
  const unsigned short h = bf16r(acc);
  attn_hi[idx] = h;
  attn_lo[idx] = bf16r(acc - bf16f(h));
}

// ---------------------------------------------------------------------------
// Kernel D: output projection via bf16 hi/lo MFMA (same structure as projmm).
// ---------------------------------------------------------------------------
__global__ __launch_bounds__(256)
void outmm_kernel(const unsigned short* __restrict__ attn_hi,
                  const unsigned short* __restrict__ attn_lo,
                  const unsigned short* __restrict__ cvt_hi,
                  const unsigned short* __restrict__ cvt_lo,
                  const float* __restrict__ bias,
                  float* __restrict__ out) {
  const int n0 = blockIdx.x * 64;  // 0..511
  const int w = threadIdx.x >> 6;
  const int lane = threadIdx.x & 63;
  const int quad = lane >> 4, n15 = lane & 15;
  const int m0 = blockIdx.y * 64 + w * 16;

  const unsigned short* __restrict__ Bh = cvt_hi + 2359296;
  const unsigned short* __restrict__ Bl = cvt_lo + 2359296;

  f32x4 acc[4];
#pragma unroll
  for (int nt = 0; nt < 4; ++nt) acc[nt] = (f32x4){0.f, 0.f, 0.f, 0.f};

  const int arow = (m0 + n15) * 512;
  for (int k0 = 0; k0 < 512; k0 += 32) {
    const int kq = k0 + quad * 8;
    short8 ah = *(const short8*)&attn_hi[arow + kq];
    short8 al = *(const short8*)&attn_lo[arow + kq];
#pragma unroll
    for (int nt = 0; nt < 4; ++nt) {
      const int brow = (n0 + nt * 16 + n15) * 512;
      short8 bh = *(const short8*)&Bh[brow + kq];
      short8 bl = *(const short8*)&Bl[brow + kq];
      acc[nt] = __builtin_amdgcn_mfma_f32_16x16x32_bf16(ah, bh, acc[nt], 0, 0, 0);
      acc[nt] = __builtin_amdgcn_mfma_f32_16x16x32_bf16(ah, bl, acc[nt], 0, 0, 0);
      acc[nt] = __builtin_amdgcn_mfma_f32_16x16x32_bf16(al, bh, acc[nt], 0, 0, 0);
    }
  }

#pragma unroll
  for (int nt = 0; nt < 4; ++nt) {
    const int j = n0 + nt * 16 + n15;
    const float bj = bias[j];
#pragma unroll
    for (int r = 0; r < 4; ++r) {
      const int row = m0 + quad * 4 + r;
      out[(size_t)row * 512 + j] = acc[nt][r] + bj;
    }
  }
}

extern "C" void kernel_launch(void* const* d_in, const int* in_sizes, int n_in,
                              void* d_out, int out_size, void* d_ws,
                              size_t ws_size, hipStream_t stream) {
  const float* query = (const float*)d_in[0];
  const float* key   = (const float*)d_in[1];
  const float* value = (const float*)d_in[2];
  const float* cbias = (const float*)d_in[3];
  const float* W     = (const float*)d_in[4];
  const float* pb    = (const float*)d_in[5];
  const float* out_w = (const float*)d_in[6];
  const float* out_b = (const float*)d_in[7];
  float* out = (float*)d_out;

  float* ws = (float*)d_ws;
  float* qh = ws;                                              // 524288 f
  float* kh = ws + 524288;                                     // 524288 f
  unsigned short* vh = (unsigned short*)(ws + 1048576);        // 262144 f
  unsigned short* cvt_hi = (unsigned short*)(ws + 1310720);    // 1310720 f
  unsigned short* cvt_lo = (unsigned short*)(ws + 2621440);    // 1310720 f
  // Aliases over regions dead after projmm:
  //  fusedb occupies cvt_hi bf16 slots [0, 2097152) (X+W region; out_w region
  //  at [2359296, 2621440) stays live for outmm).
  //  attn hi/lo occupy cvt_lo bf16 slots [0, 1048576) (X region).
  float* fusedb = (float*)cvt_hi;             // 1048576 f
  unsigned short* attn_hi = cvt_lo;           // 524288 bf16
  unsigned short* attn_lo = cvt_lo + 524288;  // 524288 bf16

  convert_kernel<<<2560, 256, 0, stream>>>(query, key, value, W, out_w,
                                           cvt_hi, cvt_lo);
  projmm_kernel<<<dim3(24, 16), 256, 0, stream>>>(cvt_hi, cvt_lo, pb, qh, kh,
                                                  vh);
  score_kernel<<<2048, 256, 0, stream>>>(qh, kh, vh, cbias, fusedb);
  softmax_attn_kernel<<<8192, 64, 0, stream>>>(fusedb, qh, attn_hi, attn_lo);
  outmm_kernel<<<dim3(8, 16), 256, 0, stream>>>(attn_hi, attn_lo, cvt_hi,
                                                cvt_lo, out_b, out);
}